// Round 3
// baseline (1253.515 us; speedup 1.0000x reference)
//
#include <hip/hip_runtime.h>
#include <hip/hip_bf16.h>

// Bahdanau attention, MI355X.
//   1. cvt Wk fp32 -> bf16 (tiny)
//   2. query = dh @ Wq^T (fp32, wave-per-row coalesced)
//   3. keys GEMM: 256x256 tile, BK=64, 8 waves, 8-phase schedule.
//      A is reg-staged DIRECTLY from fp32 enc (cvt in-register) -> no
//      separate enc conversion pass.  All global loads compiler-waited
//      (no global_load_lds, no manual vmcnt).  Raw s_barrier with memory
//      clobber; lgkmcnt(0) before publish barriers.  XOR-swizzled LDS.
//      Fused epilogue: energy[b,s] += sum_h tanh(q+keys)*v (atomicAdd)
//   4. softmax over S (with mask)
//   5. context = attn @ enc (fp32)

#define B_   64
#define S_   1024
#define HID_ 1024
#define ENC_ 2048

typedef unsigned short u16;
typedef float  f32x4  __attribute__((ext_vector_type(4)));
typedef __bf16 bf16x8 __attribute__((ext_vector_type(8)));
typedef u16    u16x8  __attribute__((ext_vector_type(8)));

__device__ __forceinline__ u16 f2bf(float f) {
    unsigned u = __float_as_uint(f);
    u += 0x7FFFu + ((u >> 16) & 1u);   // RNE
    return (u16)(u >> 16);
}

#define BARM() asm volatile("s_barrier" ::: "memory")
#define LGB()  asm volatile("s_waitcnt lgkmcnt(0)\n\ts_barrier" ::: "memory")

// ---------------- fp32 -> bf16 convert (Wk only) ----------------
__global__ __launch_bounds__(256) void cvt_kernel(const float* __restrict__ in,
                                                  u16* __restrict__ out, long n8) {
    long stride = (long)gridDim.x * blockDim.x;
    for (long i = (long)blockIdx.x * blockDim.x + threadIdx.x; i < n8; i += stride) {
        const float4* p = (const float4*)(in + (i << 3));
        float4 a = p[0], c = p[1];
        u16x8 o;
        o[0] = f2bf(a.x); o[1] = f2bf(a.y); o[2] = f2bf(a.z); o[3] = f2bf(a.w);
        o[4] = f2bf(c.x); o[5] = f2bf(c.y); o[6] = f2bf(c.z); o[7] = f2bf(c.w);
        *(u16x8*)(out + (i << 3)) = o;
    }
}

// ---------------- query: one wave per h row, coalesced --------------------
__global__ __launch_bounds__(256) void query_kernel(const float* __restrict__ dh,
                                                    const float* __restrict__ Wq,
                                                    float* __restrict__ q) {
    int w = threadIdx.x >> 6, l = threadIdx.x & 63;
    int h = (blockIdx.x << 2) + w;
    float4 wv[4];
    const float* wrow = Wq + (size_t)h * HID_;
    #pragma unroll
    for (int it = 0; it < 4; ++it) wv[it] = *(const float4*)(wrow + (it << 8) + (l << 2));
    for (int b = 0; b < 64; ++b) {
        const float* dr = dh + (b << 10);
        float s = 0.f;
        #pragma unroll
        for (int it = 0; it < 4; ++it) {
            float4 d = *(const float4*)(dr + (it << 8) + (l << 2));
            s += wv[it].x * d.x + wv[it].y * d.y + wv[it].z * d.z + wv[it].w * d.w;
        }
        #pragma unroll
        for (int off = 32; off >= 1; off >>= 1) s += __shfl_xor(s, off);
        if (l == 0) q[(b << 10) + h] = s;
    }
}

// ---------------- keys GEMM, 8-phase 256^2 template, reg-staged A ---------
// A = enc fp32 [65536][2048], Bw = wk_bf [1024][2048], K contiguous.
// LDS 128 KiB: buf0/buf1, each [A0|A1|B0|B1] halves of 128x64 bf16 = 16 KiB.
// Swizzle: granule g of row r lives at linear granule g^(r&7); staging
// loads the swizzle-inverse source column; reads XOR the column.
__global__ __launch_bounds__(512, 2) void keys_gemm(const float* __restrict__ A,
                                                    const u16* __restrict__ Bw,
                                                    const float* __restrict__ q,
                                                    const float* __restrict__ v,
                                                    float* __restrict__ energy) {
    __shared__ char smem[131072];
    int bid = blockIdx.x;
    int wg = ((bid & 7) << 7) + (bid >> 3);          // XCD swizzle, 1024%8==0
    int mt = wg >> 2, nt = wg & 3;
    int t = threadIdx.x;
    int w = t >> 6, l = t & 63;
    int wm = w >> 2, wn = w & 3;                     // 2M x 4N wave grid
    int lhi = l >> 4, llo = l & 15;
    const float* Apan = A  + ((size_t)mt << 8) * ENC_;
    const u16*   Bpan = Bw + ((size_t)nt << 8) * ENC_;

    // staging thread constants
    int r0 = t >> 3;                                 // rows 0..63  (sub-half0)
    int r1 = 64 + r0;                                // rows 64..127 (sub-half1)
    int c0 = (((t & 7) ^ (r0 & 7)) << 3);            // swizzle-inverse src col

    // frag read bases
    char* aHalf = smem + wm * 16384;                 // + buf*65536
    char* bHalf = smem + 32768 + (wn >> 1) * 16384;
    int bRowO = (wn & 1) << 6;
    int axor = (llo & 7) << 4;

    f32x4 acc[8][4] = {};
    bf16x8 a[4][2], b01e[2][2], b01o[2][2], b23[2][2];

    struct AFrag { float4 x0, x1, y0, y1; };
    struct BFrag { u16x8 x, y; };
    AFrag sA;
    BFrag sB;

    auto loadA = [&](int rowBase, int kt) -> AFrag {
        const float* p0 = Apan + (size_t)(rowBase + r0) * ENC_ + kt + c0;
        const float* p1 = Apan + (size_t)(rowBase + r1) * ENC_ + kt + c0;
        AFrag f;
        f.x0 = *(const float4*)p0; f.x1 = *(const float4*)(p0 + 4);
        f.y0 = *(const float4*)p1; f.y1 = *(const float4*)(p1 + 4);
        return f;
    };
    auto writeA = [&](const AFrag& f, int ldsOfs) {
        bf16x8 o0, o1;
        o0[0] = (__bf16)f.x0.x; o0[1] = (__bf16)f.x0.y;
        o0[2] = (__bf16)f.x0.z; o0[3] = (__bf16)f.x0.w;
        o0[4] = (__bf16)f.x1.x; o0[5] = (__bf16)f.x1.y;
        o0[6] = (__bf16)f.x1.z; o0[7] = (__bf16)f.x1.w;
        o1[0] = (__bf16)f.y0.x; o1[1] = (__bf16)f.y0.y;
        o1[2] = (__bf16)f.y0.z; o1[3] = (__bf16)f.y0.w;
        o1[4] = (__bf16)f.y1.x; o1[5] = (__bf16)f.y1.y;
        o1[6] = (__bf16)f.y1.z; o1[7] = (__bf16)f.y1.w;
        *(bf16x8*)(smem + ldsOfs + (t << 4)) = o0;
        *(bf16x8*)(smem + ldsOfs + 8192 + (t << 4)) = o1;
    };
    auto loadB = [&](int rowBase, int kt) -> BFrag {
        BFrag f;
        f.x = *(const u16x8*)(Bpan + (size_t)(rowBase + r0) * ENC_ + kt + c0);
        f.y = *(const u16x8*)(Bpan + (size_t)(rowBase + r1) * ENC_ + kt + c0);
        return f;
    };
    auto writeB = [&](const BFrag& f, int ldsOfs) {
        *(u16x8*)(smem + ldsOfs + (t << 4)) = f.x;
        *(u16x8*)(smem + ldsOfs + 8192 + (t << 4)) = f.y;
    };

    auto LDA = [&](int bufofs, int ibase) {
        #pragma unroll
        for (int ii = 0; ii < 4; ++ii)
            #pragma unroll
            for (int k = 0; k < 2; ++k)
                a[ii][k] = *(const bf16x8*)(aHalf + bufofs +
                    ((llo + ((ibase + ii) << 4)) << 7) + ((((k << 2) + lhi) << 4) ^ axor));
    };
    auto LDB = [&](bf16x8 (&bb)[2][2], int bufofs, int jbase) {
        #pragma unroll
        for (int j = 0; j < 2; ++j)
            #pragma unroll
            for (int k = 0; k < 2; ++k)
                bb[j][k] = *(const bf16x8*)(bHalf + bufofs +
                    ((bRowO + llo + ((jbase + j) << 4)) << 7) + ((((k << 2) + lhi) << 4) ^ axor));
    };
    auto MMq = [&](bf16x8 (&bb)[2][2], int ibase, int jbase) {
        __builtin_amdgcn_s_setprio(1);
        #pragma unroll
        for (int ii = 0; ii < 4; ++ii)
            #pragma unroll
            for (int j = 0; j < 2; ++j)
                #pragma unroll
                for (int k = 0; k < 2; ++k)
                    acc[ibase + ii][jbase + j] = __builtin_amdgcn_mfma_f32_16x16x32_bf16(
                        a[ii][k], bb[j][k], acc[ibase + ii][jbase + j], 0, 0, 0);
        __builtin_amdgcn_s_setprio(0);
    };

    // ---- prologue: buf0 <- tile0 (A0,A1,B0,B1); buf1.B0 <- tile1; sB pending
    {
        AFrag pA;
        BFrag pB;
        pA = loadA(0, 0);    writeA(pA, 0);
        pA = loadA(128, 0);  writeA(pA, 16384);
        pB = loadB(0, 0);    writeB(pB, 32768);
        pB = loadB(128, 0);  writeB(pB, 49152);
        pB = loadB(0, 64);   writeB(pB, 65536 + 32768);
        sB = loadB(128, 64);                      // B1-odd tile1, written in P1
    }
    LGB();
    LDB(b01e, 0, 0);                               // preload buf0 j01 frags

    #pragma unroll 1
    for (int u = 0; u < 16; ++u) {
        int ktA = u << 7, ktB = ktA + 64;
        int ks2 = ktA + 128; if (ks2 >= ENC_) ks2 -= 128;   // tile 2u+2
        int ks3 = ktA + 192; if (ks3 >= ENC_) ks3 -= 128;   // tile 2u+3

        // P1: compute buf0 (i0-3 x j01)
        LDA(0, 0);
        writeB(sB, 65536 + 49152);   sA = loadA(0, ktB);
        BARM(); MMq(b01e, 0, 0); LGB();
        // P2: (i0-3 x j23)
        LDB(b23, 0, 2);
        writeA(sA, 65536);           sA = loadA(128, ktB);
        BARM(); MMq(b23, 0, 2); LGB();
        // P3: (i4-7 x j23)
        LDA(0, 4);
        writeA(sA, 65536 + 16384);   sB = loadB(0, ks2);
        BARM(); MMq(b23, 4, 2); LGB();
        // P4: (i4-7 x j01); preload buf1 j01
        LDB(b01o, 65536, 0);
        writeB(sB, 32768);           sB = loadB(128, ks2);
        BARM(); MMq(b01e, 4, 0); LGB();
        // P5: compute buf1 (i0-3 x j01)
        LDA(65536, 0);
        writeB(sB, 49152);           sA = loadA(0, ks2);
        BARM(); MMq(b01o, 0, 0); LGB();
        // P6: (i0-3 x j23)
        LDB(b23, 65536, 2);
        writeA(sA, 0);               sA = loadA(128, ks2);
        BARM(); MMq(b23, 0, 2); LGB();
        // P7: (i4-7 x j23)
        LDA(65536, 4);
        writeA(sA, 16384);           sB = loadB(0, ks3);
        BARM(); MMq(b23, 4, 2); LGB();
        // P8: (i4-7 x j01); preload next buf0 j01
        LDB(b01e, 0, 0);
        writeB(sB, 65536 + 32768);   sB = loadB(128, ks3);
        BARM(); MMq(b01o, 4, 0); LGB();
    }

    // epilogue: energy[m] += sum_h tanh(q[b,h] + keys[m,h]) * v[h]
    int b = mt >> 2;
    float qv[4], vv[4];
    #pragma unroll
    for (int j = 0; j < 4; ++j) {
        int h = (nt << 8) + (wn << 6) + (j << 4) + llo;
        qv[j] = q[(b << 10) + h];
        vv[j] = v[h];
    }
    #pragma unroll
    for (int i = 0; i < 8; ++i) {
        #pragma unroll
        for (int r = 0; r < 4; ++r) {
            float part = 0.f;
            #pragma unroll
            for (int j = 0; j < 4; ++j)
                part += tanhf(qv[j] + acc[i][j][r]) * vv[j];
            part += __shfl_down(part, 8);
            part += __shfl_down(part, 4);
            part += __shfl_down(part, 2);
            part += __shfl_down(part, 1);
            if (llo == 0) {
                int m = (mt << 8) + (wm << 7) + (i << 4) + (lhi << 2) + r;
                atomicAdd(&energy[m], part);
            }
        }
    }
}

// ---------------- softmax over S (one block per b) ------------------------
__global__ __launch_bounds__(256) void softmax_kernel(const float* __restrict__ energy,
                                                      const int* __restrict__ mask,
                                                      float* __restrict__ attn) {
    int b = blockIdx.x, t = threadIdx.x;
    int w = t >> 6, l = t & 63;
    __shared__ float rmax[4], rsum[4];
    float4 e = *(const float4*)(energy + (b << 10) + (t << 2));
    int4 mk = *(const int4*)(mask + (b << 10) + (t << 2));
    if (mk.x == 0) e.x = -1e10f;
    if (mk.y == 0) e.y = -1e10f;
    if (mk.z == 0) e.z = -1e10f;
    if (mk.w == 0) e.w = -1e10f;
    float mx = fmaxf(fmaxf(e.x, e.y), fmaxf(e.z, e.w));
    for (int off = 32; off >= 1; off >>= 1) mx = fmaxf(mx, __shfl_xor(mx, off));
    if (l == 0) rmax[w] = mx;
    __syncthreads();
    mx = fmaxf(fmaxf(rmax[0], rmax[1]), fmaxf(rmax[2], rmax[3]));
    float4 ex;
    ex.x = expf(e.x - mx); ex.y = expf(e.y - mx);
    ex.z = expf(e.z - mx); ex.w = expf(e.w - mx);
    float sm = ex.x + ex.y + ex.z + ex.w;
    for (int off = 32; off >= 1; off >>= 1) sm += __shfl_xor(sm, off);
    if (l == 0) rsum[w] = sm;
    __syncthreads();
    sm = rsum[0] + rsum[1] + rsum[2] + rsum[3];
    float inv = 1.0f / sm;
    ex.x *= inv; ex.y *= inv; ex.z *= inv; ex.w *= inv;
    *(float4*)(attn + (b << 10) + (t << 2)) = ex;
}

// ---------------- context = attn @ enc (fp32) -----------------------------
__global__ __launch_bounds__(256) void context_kernel(const float* __restrict__ enc,
                                                      const float* __restrict__ attn,
                                                      float* __restrict__ ctx) {
    int b = blockIdx.y;
    int s0 = blockIdx.x << 7;
    int t = threadIdx.x;
    int e0 = t << 3;
    float4 a0 = {0.f, 0.f, 0.f, 0.f}, a1 = {0.f, 0.f, 0.f, 0.f};
    const float* base = enc + ((size_t)((b << 10) + s0)) * ENC_ + e0;
    const float* wp = attn + (b << 10) + s0;
    for (int s = 0; s < 128; ++s) {
        float wgt = wp[s];
        float4 u0 = *(const float4*)(base + (size_t)s * ENC_);
        float4 u1 = *(const float4*)(base + (size_t)s * ENC_ + 4);
        a0.x += wgt * u0.x; a0.y += wgt * u0.y; a0.z += wgt * u0.z; a0.w += wgt * u0.w;
        a1.x += wgt * u1.x; a1.y += wgt * u1.y; a1.z += wgt * u1.z; a1.w += wgt * u1.w;
    }
    float* cb = ctx + (b << 11) + e0;
    atomicAdd(&cb[0], a0.x); atomicAdd(&cb[1], a0.y);
    atomicAdd(&cb[2], a0.z); atomicAdd(&cb[3], a0.w);
    atomicAdd(&cb[4], a1.x); atomicAdd(&cb[5], a1.y);
    atomicAdd(&cb[6], a1.z); atomicAdd(&cb[7], a1.w);
}

extern "C" void kernel_launch(void* const* d_in, const int* in_sizes, int n_in,
                              void* d_out, int out_size, void* d_ws, size_t ws_size,
                              hipStream_t stream) {
    const float* dh   = (const float*)d_in[0];
    const float* enc  = (const float*)d_in[1];
    const int*   mask = (const int*)d_in[2];
    const float* Wq   = (const float*)d_in[3];
    const float* Wk   = (const float*)d_in[4];
    const float* v    = (const float*)d_in[5];
    float* out  = (float*)d_out;
    float* ctx  = out;                 // [64,2048]
    float* attn = out + B_ * ENC_;     // [64,1024]

    const size_t WK_BF_BYTES  = (size_t)HID_ * ENC_ * 2;
    const size_t Q_BYTES      = (size_t)B_ * HID_ * 4;
    const size_t E_BYTES      = (size_t)B_ * S_ * 4;
    if (ws_size < WK_BF_BYTES + Q_BYTES + E_BYTES) return;

    char* ws = (char*)d_ws;
    u16*   wk_bf  = (u16*)ws;
    float* qbuf   = (float*)(ws + WK_BF_BYTES);
    float* energy = (float*)(ws + WK_BF_BYTES + Q_BYTES);

    hipMemsetAsync(energy, 0, E_BYTES, stream);
    hipMemsetAsync(d_out, 0, (size_t)out_size * 4, stream);

    cvt_kernel<<<128, 256, 0, stream>>>(Wk, wk_bf, (long)((size_t)HID_ * ENC_ / 8));
    query_kernel<<<256, 256, 0, stream>>>(dh, Wq, qbuf);
    keys_gemm<<<1024, 512, 0, stream>>>(enc, wk_bf, qbuf, v, energy);
    softmax_kernel<<<B_, 256, 0, stream>>>(energy, mask, attn);
    context_kernel<<<dim3(8, B_), 256, 0, stream>>>(enc, attn, ctx);
}